// Round 9
// baseline (1618.916 us; speedup 1.0000x reference)
//
#include <hip/hip_runtime.h>

#define NPIX   65536          // B*H*W
#define CCH    64
#define KCODE  1024
#define HW     4096
#define Q_ELEMS 4194304
#define LOSS0_OFF 4194304
#define LOSS1_OFF 4194305
#define IDX_OFF   4194306
#define PTILE  16             // pixels per block

// numpy pairwise_sum middle branch for n=64 on squares (bit-exact np.sum(x*x))
template <typename F>
__device__ __forceinline__ float np_pairwise64_sq(F v) {
    float r[8];
#pragma unroll
    for (int j = 0; j < 8; ++j) r[j] = __fmul_rn(v(j), v(j));
#pragma unroll
    for (int i = 8; i < 64; i += 8) {
#pragma unroll
        for (int j = 0; j < 8; ++j)
            r[j] = __fadd_rn(r[j], __fmul_rn(v(i + j), v(i + j)));
    }
    return __fadd_rn(
        __fadd_rn(__fadd_rn(r[0], r[1]), __fadd_rn(r[2], r[3])),
        __fadd_rn(__fadd_rn(r[4], r[5]), __fadd_rn(r[6], r[7])));
}

// prep v2 (verified absmax 0): LDS-tile transpose, coalesced on both sides.
__global__ void prep_kernel(const float* __restrict__ emb,
                            float* __restrict__ se, float* __restrict__ et,
                            float* __restrict__ out) {
    __shared__ float s_e[64][65];                      // +pad: conflict-free both axes
    const int t  = threadIdx.x;
    const int k0 = blockIdx.x << 6;
#pragma unroll
    for (int i = 0; i < 4; ++i) {
        const int q = (i << 8) + t;                    // float4 index 0..1023
        const float4 v = reinterpret_cast<const float4*>(emb + ((size_t)k0 << 6))[q];
        const int r = q >> 4, c4 = (q & 15) << 2;
        s_e[r][c4] = v.x; s_e[r][c4 + 1] = v.y; s_e[r][c4 + 2] = v.z; s_e[r][c4 + 3] = v.w;
    }
    __syncthreads();
    if (t < 64)
        se[k0 + t] = np_pairwise64_sq([&](int i) { return s_e[t][i]; });
#pragma unroll
    for (int i = 0; i < 16; ++i) {
        const int n = (i << 8) + t;                    // 0..4095
        const int c = n >> 6, kk = n & 63;
        et[((size_t)c << 10) + k0 + kk] = s_e[kk][c];  // wave: 256B contiguous
    }
    if ((blockIdx.x | t) == 0) { out[LOSS0_OFF] = 0.f; out[LOSS1_OFF] = 0.f; }
}

// main: EXACT R8 structure (130.6us, VGPR 52, no spills). ONLY change:
// launch_bounds 2nd arg 4 -> 8. Measured across R5/R8/R1 at fixed structure,
// resident waves/SIMD ~= 0.78 * this arg even when LDS/VGPR permit more --
// the arg acts as a residency cap on this toolchain. R3 structure demands
// only 52 VGPR, under the 64-VGPR cap that 8 waves/SIMD requires, so unlike
// R1 (90-VGPR structure squeezed to 32 -> spills) this should fit clean.
// Tripwire: FETCH > 25MB or VGPR <= 40 => allocator squeezed, back off to 6.
__launch_bounds__(256, 8)
__global__ void vq_kernel(const float* __restrict__ z,
                          const float* __restrict__ emb,
                          const float* __restrict__ se,
                          const float* __restrict__ et,
                          float* __restrict__ out) {
    __shared__ float s_szz[PTILE];
    __shared__ unsigned long long s_cand[PTILE][129];  // halved via shfl pre-reduce; +pad
    __shared__ unsigned long long s_part[PTILE][16];
    __shared__ unsigned int s_k[PTILE];
    __shared__ float s_red[4];

    const int t    = threadIdx.x;
    const int lane = t & 63;
    const int wave = t >> 6;
    const int pg0  = blockIdx.x * PTILE;
    const int b    = pg0 >> 12;
    const int hw0  = pg0 & 4095;
    const float* zb = z + (size_t)b * CCH * HW + hw0;  // zb[c*HW + p], wave-uniform

    // szz for the block's 16 pixels (np order), lanes 0..15 of wave 0
    if (t < PTILE)
        s_szz[t] = np_pairwise64_sq([&](int i) { return zb[(size_t)i * HW + t]; });
    __syncthreads();

    // ---- main accumulation: acc[j][p] = sum_c z[c][p] * E^T[c][4t+j] ----
    float acc[4][PTILE];
#pragma unroll
    for (int j = 0; j < 4; ++j)
#pragma unroll
        for (int p = 0; p < PTILE; ++p) acc[j][p] = 0.f;

    const float* ecol = et + (t << 2);                 // 4 consecutive codes
#pragma unroll 4
    for (int c = 0; c < CCH; ++c) {
        const float4 evv = *reinterpret_cast<const float4*>(ecol + (c << 10));
        const float ev[4] = {evv.x, evv.y, evv.z, evv.w};
        float zrow[PTILE];                              // uniform -> s_load_dwordx16
#pragma unroll
        for (int p = 0; p < PTILE; ++p) zrow[p] = zb[(size_t)c * HW + p];
#pragma unroll
        for (int j = 0; j < 4; ++j)
#pragma unroll
            for (int p = 0; p < PTILE; ++p)
                acc[j][p] = __builtin_fmaf(zrow[p], ev[j], acc[j][p]);  // same chain as R2
    }

    // ---- finalize distances + per-thread best (tail; acc dies into best) ----
    float szzv[PTILE];
#pragma unroll
    for (int p = 0; p < PTILE; ++p) szzv[p] = s_szz[p];
    const float4 se4v = *reinterpret_cast<const float4*>(se + (t << 2));
    const float se4[4] = {se4v.x, se4v.y, se4v.z, se4v.w};

    unsigned long long best[PTILE];
#pragma unroll
    for (int p = 0; p < PTILE; ++p) best[p] = ~0ULL;

#pragma unroll
    for (int j = 0; j < 4; ++j) {
        const int kk = (t << 2) + j;
#pragma unroll
        for (int p = 0; p < PTILE; ++p) {
            // d = fl( fl(szz+se) - 2*dot )  (identical algebra to R2, absmax 0)
            float d = __fsub_rn(__fadd_rn(szzv[p], se4[j]), __fadd_rn(acc[j][p], acc[j][p]));
            unsigned long long cand =
                ((unsigned long long)__float_as_uint(d) << 32) | (unsigned)kk;
            best[p] = cand < best[p] ? cand : best[p];   // d>0 -> bit-order == value-order
        }
    }

    // stage 1.5: one butterfly step in registers (exact: u64 min over same set)
#pragma unroll
    for (int p = 0; p < PTILE; ++p) {
        unsigned long long o = __shfl_xor(best[p], 1, 64);
        best[p] = o < best[p] ? o : best[p];
    }
    if ((t & 1) == 0) {
#pragma unroll
        for (int p = 0; p < PTILE; ++p) s_cand[p][t >> 1] = best[p];
    }
    __syncthreads();

    {   // stage 2: 256 threads, each folds 8 of the 128 candidates of pixel t&15
        const int p = t & 15, g = t >> 4;
        unsigned long long m = s_cand[p][(g << 3)];
#pragma unroll
        for (int u = 1; u < 8; ++u) {
            unsigned long long v = s_cand[p][(g << 3) + u];
            m = v < m ? v : m;
        }
        s_part[p][g] = m;
    }
    __syncthreads();

    if (t < PTILE) {   // stage 3: final per-pixel min; packed low bits = first-index k
        unsigned long long m = s_part[t][0];
#pragma unroll
        for (int g = 1; g < 16; ++g) {
            unsigned long long v = s_part[t][g];
            m = v < m ? v : m;
        }
        const unsigned int k = (unsigned int)m;
        s_k[t] = k;
        out[IDX_OFF + pg0 + t] = (float)k;
    }
    __syncthreads();

    // epilogue: thread t -> pixel p=t&15, channels c = (t>>4) + 16u
    float lsum = 0.f;
    {
        const int p = t & 15, g = t >> 4;
        const int k = (int)s_k[p];
#pragma unroll
        for (int u = 0; u < 4; ++u) {
            const int c = g + (u << 4);
            float e    = emb[(size_t)k * CCH + c];
            float zc   = zb[(size_t)c * HW + p];
            float diff = __fsub_rn(e, zc);               // STE rounding as in R2
            out[((size_t)(b * CCH + c)) * HW + hw0 + p] = __fadd_rn(zc, diff);
            lsum = __builtin_fmaf(diff, diff, lsum);
        }
    }
#pragma unroll
    for (int off = 32; off > 0; off >>= 1) lsum += __shfl_down(lsum, off, 64);
    if (lane == 0) s_red[wave] = lsum;
    __syncthreads();
    if (t == 0) {
        float v = (s_red[0] + s_red[1] + s_red[2] + s_red[3]) * (1.0f / (float)Q_ELEMS);
        atomicAdd(out + LOSS0_OFF, v);   // codebook_loss
        atomicAdd(out + LOSS1_OFF, v);   // commitment_loss (same forward value)
    }
}

extern "C" void kernel_launch(void* const* d_in, const int* in_sizes, int n_in,
                              void* d_out, int out_size, void* d_ws, size_t ws_size,
                              hipStream_t stream) {
    const float* z   = (const float*)d_in[0];
    const float* emb = (const float*)d_in[1];
    float* out = (float*)d_out;
    float* se  = (float*)d_ws;                 // 1024 floats
    float* et  = se + KCODE;                   // 65536 floats (E^T)

    prep_kernel<<<dim3(16), dim3(256), 0, stream>>>(emb, se, et, out);
    vq_kernel<<<dim3(NPIX / PTILE), dim3(256), 0, stream>>>(z, emb, se, et, out);
}

// Round 10
// 479.806 us; speedup vs baseline: 3.3741x; 3.3741x over previous
//
#include <hip/hip_runtime.h>

#define NPIX   65536          // B*H*W
#define CCH    64
#define KCODE  1024
#define HW     4096
#define Q_ELEMS 4194304
#define LOSS0_OFF 4194304
#define LOSS1_OFF 4194305
#define IDX_OFF   4194306
#define PTILE  16             // pixels per block

// numpy pairwise_sum middle branch for n=64 on squares (bit-exact np.sum(x*x))
template <typename F>
__device__ __forceinline__ float np_pairwise64_sq(F v) {
    float r[8];
#pragma unroll
    for (int j = 0; j < 8; ++j) r[j] = __fmul_rn(v(j), v(j));
#pragma unroll
    for (int i = 8; i < 64; i += 8) {
#pragma unroll
        for (int j = 0; j < 8; ++j)
            r[j] = __fadd_rn(r[j], __fmul_rn(v(i + j), v(i + j)));
    }
    return __fadd_rn(
        __fadd_rn(__fadd_rn(r[0], r[1]), __fadd_rn(r[2], r[3])),
        __fadd_rn(__fadd_rn(r[4], r[5]), __fadd_rn(r[6], r[7])));
}

// prep v2 (verified absmax 0): LDS-tile transpose, coalesced on both sides.
__global__ void prep_kernel(const float* __restrict__ emb,
                            float* __restrict__ se, float* __restrict__ et,
                            float* __restrict__ out) {
    __shared__ float s_e[64][65];                      // +pad: conflict-free both axes
    const int t  = threadIdx.x;
    const int k0 = blockIdx.x << 6;
#pragma unroll
    for (int i = 0; i < 4; ++i) {
        const int q = (i << 8) + t;                    // float4 index 0..1023
        const float4 v = reinterpret_cast<const float4*>(emb + ((size_t)k0 << 6))[q];
        const int r = q >> 4, c4 = (q & 15) << 2;
        s_e[r][c4] = v.x; s_e[r][c4 + 1] = v.y; s_e[r][c4 + 2] = v.z; s_e[r][c4 + 3] = v.w;
    }
    __syncthreads();
    if (t < 64)
        se[k0 + t] = np_pairwise64_sq([&](int i) { return s_e[t][i]; });
#pragma unroll
    for (int i = 0; i < 16; ++i) {
        const int n = (i << 8) + t;                    // 0..4095
        const int c = n >> 6, kk = n & 63;
        et[((size_t)c << 10) + k0 + kk] = s_e[kk][c];  // wave: 256B contiguous
    }
    if ((blockIdx.x | t) == 0) { out[LOSS0_OFF] = 0.f; out[LOSS1_OFF] = 0.f; }
}

// main: EXACT R8 structure (130.6us @ W=4, VGPR 52, no spills). ONLY change:
// launch_bounds 2nd arg -> 6.
// Toolchain facts established: W=8 => allocator forces 32 VGPR => spills
// (R1, R9: FETCH 0.4-2.6 GB). W=6 budget = 512/6 ~= 85 VGPR >= 52 demanded,
// so no squeeze expected; residency pattern (occ ~= 0.78 x W) predicts
// ~4.7 waves/SIMD vs 3.0 at W=4.
// Tripwire: VGPR <= 48 or FETCH > 25 MB => squeezed; revert to W=4.
__launch_bounds__(256, 6)
__global__ void vq_kernel(const float* __restrict__ z,
                          const float* __restrict__ emb,
                          const float* __restrict__ se,
                          const float* __restrict__ et,
                          float* __restrict__ out) {
    __shared__ float s_szz[PTILE];
    __shared__ unsigned long long s_cand[PTILE][129];  // halved via shfl pre-reduce; +pad
    __shared__ unsigned long long s_part[PTILE][16];
    __shared__ unsigned int s_k[PTILE];
    __shared__ float s_red[4];

    const int t    = threadIdx.x;
    const int lane = t & 63;
    const int wave = t >> 6;
    const int pg0  = blockIdx.x * PTILE;
    const int b    = pg0 >> 12;
    const int hw0  = pg0 & 4095;
    const float* zb = z + (size_t)b * CCH * HW + hw0;  // zb[c*HW + p], wave-uniform

    // szz for the block's 16 pixels (np order), lanes 0..15 of wave 0
    if (t < PTILE)
        s_szz[t] = np_pairwise64_sq([&](int i) { return zb[(size_t)i * HW + t]; });
    __syncthreads();

    // ---- main accumulation: acc[j][p] = sum_c z[c][p] * E^T[c][4t+j] ----
    float acc[4][PTILE];
#pragma unroll
    for (int j = 0; j < 4; ++j)
#pragma unroll
        for (int p = 0; p < PTILE; ++p) acc[j][p] = 0.f;

    const float* ecol = et + (t << 2);                 // 4 consecutive codes
#pragma unroll 4
    for (int c = 0; c < CCH; ++c) {
        const float4 evv = *reinterpret_cast<const float4*>(ecol + (c << 10));
        const float ev[4] = {evv.x, evv.y, evv.z, evv.w};
        float zrow[PTILE];                              // uniform -> s_load_dwordx16
#pragma unroll
        for (int p = 0; p < PTILE; ++p) zrow[p] = zb[(size_t)c * HW + p];
#pragma unroll
        for (int j = 0; j < 4; ++j)
#pragma unroll
            for (int p = 0; p < PTILE; ++p)
                acc[j][p] = __builtin_fmaf(zrow[p], ev[j], acc[j][p]);  // same chain as R2
    }

    // ---- finalize distances + per-thread best (tail; acc dies into best) ----
    float szzv[PTILE];
#pragma unroll
    for (int p = 0; p < PTILE; ++p) szzv[p] = s_szz[p];
    const float4 se4v = *reinterpret_cast<const float4*>(se + (t << 2));
    const float se4[4] = {se4v.x, se4v.y, se4v.z, se4v.w};

    unsigned long long best[PTILE];
#pragma unroll
    for (int p = 0; p < PTILE; ++p) best[p] = ~0ULL;

#pragma unroll
    for (int j = 0; j < 4; ++j) {
        const int kk = (t << 2) + j;
#pragma unroll
        for (int p = 0; p < PTILE; ++p) {
            // d = fl( fl(szz+se) - 2*dot )  (identical algebra to R2, absmax 0)
            float d = __fsub_rn(__fadd_rn(szzv[p], se4[j]), __fadd_rn(acc[j][p], acc[j][p]));
            unsigned long long cand =
                ((unsigned long long)__float_as_uint(d) << 32) | (unsigned)kk;
            best[p] = cand < best[p] ? cand : best[p];   // d>0 -> bit-order == value-order
        }
    }

    // stage 1.5: one butterfly step in registers (exact: u64 min over same set)
#pragma unroll
    for (int p = 0; p < PTILE; ++p) {
        unsigned long long o = __shfl_xor(best[p], 1, 64);
        best[p] = o < best[p] ? o : best[p];
    }
    if ((t & 1) == 0) {
#pragma unroll
        for (int p = 0; p < PTILE; ++p) s_cand[p][t >> 1] = best[p];
    }
    __syncthreads();

    {   // stage 2: 256 threads, each folds 8 of the 128 candidates of pixel t&15
        const int p = t & 15, g = t >> 4;
        unsigned long long m = s_cand[p][(g << 3)];
#pragma unroll
        for (int u = 1; u < 8; ++u) {
            unsigned long long v = s_cand[p][(g << 3) + u];
            m = v < m ? v : m;
        }
        s_part[p][g] = m;
    }
    __syncthreads();

    if (t < PTILE) {   // stage 3: final per-pixel min; packed low bits = first-index k
        unsigned long long m = s_part[t][0];
#pragma unroll
        for (int g = 1; g < 16; ++g) {
            unsigned long long v = s_part[t][g];
            m = v < m ? v : m;
        }
        const unsigned int k = (unsigned int)m;
        s_k[t] = k;
        out[IDX_OFF + pg0 + t] = (float)k;
    }
    __syncthreads();

    // epilogue: thread t -> pixel p=t&15, channels c = (t>>4) + 16u
    float lsum = 0.f;
    {
        const int p = t & 15, g = t >> 4;
        const int k = (int)s_k[p];
#pragma unroll
        for (int u = 0; u < 4; ++u) {
            const int c = g + (u << 4);
            float e    = emb[(size_t)k * CCH + c];
            float zc   = zb[(size_t)c * HW + p];
            float diff = __fsub_rn(e, zc);               // STE rounding as in R2
            out[((size_t)(b * CCH + c)) * HW + hw0 + p] = __fadd_rn(zc, diff);
            lsum = __builtin_fmaf(diff, diff, lsum);
        }
    }
#pragma unroll
    for (int off = 32; off > 0; off >>= 1) lsum += __shfl_down(lsum, off, 64);
    if (lane == 0) s_red[wave] = lsum;
    __syncthreads();
    if (t == 0) {
        float v = (s_red[0] + s_red[1] + s_red[2] + s_red[3]) * (1.0f / (float)Q_ELEMS);
        atomicAdd(out + LOSS0_OFF, v);   // codebook_loss
        atomicAdd(out + LOSS1_OFF, v);   // commitment_loss (same forward value)
    }
}

extern "C" void kernel_launch(void* const* d_in, const int* in_sizes, int n_in,
                              void* d_out, int out_size, void* d_ws, size_t ws_size,
                              hipStream_t stream) {
    const float* z   = (const float*)d_in[0];
    const float* emb = (const float*)d_in[1];
    float* out = (float*)d_out;
    float* se  = (float*)d_ws;                 // 1024 floats
    float* et  = se + KCODE;                   // 65536 floats (E^T)

    prep_kernel<<<dim3(16), dim3(256), 0, stream>>>(emb, se, et, out);
    vq_kernel<<<dim3(NPIX / PTILE), dim3(256), 0, stream>>>(z, emb, se, et, out);
}

// Round 11
// 202.821 us; speedup vs baseline: 7.9820x; 2.3657x over previous
//
#include <hip/hip_runtime.h>

#define NPIX   65536          // B*H*W
#define CCH    64
#define KCODE  1024
#define HW     4096
#define Q_ELEMS 4194304
#define LOSS0_OFF 4194304
#define LOSS1_OFF 4194305
#define IDX_OFF   4194306
#define PTILE  16             // pixels per block

// numpy pairwise_sum middle branch for n=64 on squares (bit-exact np.sum(x*x))
template <typename F>
__device__ __forceinline__ float np_pairwise64_sq(F v) {
    float r[8];
#pragma unroll
    for (int j = 0; j < 8; ++j) r[j] = __fmul_rn(v(j), v(j));
#pragma unroll
    for (int i = 8; i < 64; i += 8) {
#pragma unroll
        for (int j = 0; j < 8; ++j)
            r[j] = __fadd_rn(r[j], __fmul_rn(v(i + j), v(i + j)));
    }
    return __fadd_rn(
        __fadd_rn(__fadd_rn(r[0], r[1]), __fadd_rn(r[2], r[3])),
        __fadd_rn(__fadd_rn(r[4], r[5]), __fadd_rn(r[6], r[7])));
}

// prep v2 (verified absmax 0): LDS-tile transpose, coalesced on both sides.
__global__ void prep_kernel(const float* __restrict__ emb,
                            float* __restrict__ se, float* __restrict__ et,
                            float* __restrict__ out) {
    __shared__ float s_e[64][65];                      // +pad: conflict-free both axes
    const int t  = threadIdx.x;
    const int k0 = blockIdx.x << 6;
#pragma unroll
    for (int i = 0; i < 4; ++i) {
        const int q = (i << 8) + t;                    // float4 index 0..1023
        const float4 v = reinterpret_cast<const float4*>(emb + ((size_t)k0 << 6))[q];
        const int r = q >> 4, c4 = (q & 15) << 2;
        s_e[r][c4] = v.x; s_e[r][c4 + 1] = v.y; s_e[r][c4 + 2] = v.z; s_e[r][c4 + 3] = v.w;
    }
    __syncthreads();
    if (t < 64)
        se[k0 + t] = np_pairwise64_sq([&](int i) { return s_e[t][i]; });
#pragma unroll
    for (int i = 0; i < 16; ++i) {
        const int n = (i << 8) + t;                    // 0..4095
        const int c = n >> 6, kk = n & 63;
        et[((size_t)c << 10) + k0 + kk] = s_e[kk][c];  // wave: 256B contiguous
    }
    if ((blockIdx.x | t) == 0) { out[LOSS0_OFF] = 0.f; out[LOSS1_OFF] = 0.f; }
}

// main: R8 structure, W=4 (the only spill-free point: allocator budget ~256/W,
// established R8/R9/R10). NEW in R11: explicit j-split -- codes {0,1} run the
// full c-loop and fold into best, then codes {2,3}. Hot-loop VGPR demand drops
// 64+ -> ~46 (acc 32 + ev 8; zrow in SGPRs), eliminating the register-parking
// shuffle traffic implied by VGPR_Count(52) < 64 live accumulators in R8.
// Each (j,p) FMA chain is the identical ascending-c sequence -> absmax 0.
__launch_bounds__(256, 4)
__global__ void vq_kernel(const float* __restrict__ z,
                          const float* __restrict__ emb,
                          const float* __restrict__ se,
                          const float* __restrict__ et,
                          float* __restrict__ out) {
    __shared__ float s_szz[PTILE];
    __shared__ unsigned long long s_cand[PTILE][129];  // halved via shfl pre-reduce; +pad
    __shared__ unsigned long long s_part[PTILE][16];
    __shared__ unsigned int s_k[PTILE];
    __shared__ float s_red[4];

    const int t    = threadIdx.x;
    const int lane = t & 63;
    const int wave = t >> 6;
    const int pg0  = blockIdx.x * PTILE;
    const int b    = pg0 >> 12;
    const int hw0  = pg0 & 4095;
    const float* zb = z + (size_t)b * CCH * HW + hw0;  // zb[c*HW + p], wave-uniform

    // szz for the block's 16 pixels (np order), lanes 0..15 of wave 0
    if (t < PTILE)
        s_szz[t] = np_pairwise64_sq([&](int i) { return zb[(size_t)i * HW + t]; });
    __syncthreads();

    float szzv[PTILE];
#pragma unroll
    for (int p = 0; p < PTILE; ++p) szzv[p] = s_szz[p];
    const float4 se4v = *reinterpret_cast<const float4*>(se + (t << 2));
    const float se4[4] = {se4v.x, se4v.y, se4v.z, se4v.w};

    unsigned long long best[PTILE];
#pragma unroll
    for (int p = 0; p < PTILE; ++p) best[p] = ~0ULL;

    const float* ecol = et + (t << 2);                 // 4 consecutive codes

#pragma unroll 1
    for (int jh = 0; jh < 2; ++jh) {                   // j-halves: {0,1}, {2,3}
        // ---- accumulation pass: acc[j][p] = sum_c z[c][p] * E^T[c][4t+2jh+j] ----
        float acc[2][PTILE];
#pragma unroll
        for (int j = 0; j < 2; ++j)
#pragma unroll
            for (int p = 0; p < PTILE; ++p) acc[j][p] = 0.f;

        const float* ej = ecol + (jh << 1);
#pragma unroll 4
        for (int c = 0; c < CCH; ++c) {
            const float2 evv = *reinterpret_cast<const float2*>(ej + (c << 10));
            const float ev[2] = {evv.x, evv.y};
            float zrow[PTILE];                          // uniform -> s_load_dwordx16
#pragma unroll
            for (int p = 0; p < PTILE; ++p) zrow[p] = zb[(size_t)c * HW + p];
#pragma unroll
            for (int j = 0; j < 2; ++j)
#pragma unroll
                for (int p = 0; p < PTILE; ++p)
                    acc[j][p] = __builtin_fmaf(zrow[p], ev[j], acc[j][p]);  // same chain as R8
        }

        // fold this half's distances into best (acc dies here)
#pragma unroll
        for (int j = 0; j < 2; ++j) {
            const int kk = (t << 2) + (jh << 1) + j;
#pragma unroll
            for (int p = 0; p < PTILE; ++p) {
                // d = fl( fl(szz+se) - 2*dot )  (identical algebra to R8, absmax 0)
                float d = __fsub_rn(__fadd_rn(szzv[p], se4[(jh << 1) + j]),
                                    __fadd_rn(acc[j][p], acc[j][p]));
                unsigned long long cand =
                    ((unsigned long long)__float_as_uint(d) << 32) | (unsigned)kk;
                best[p] = cand < best[p] ? cand : best[p];  // d>0 -> bit-order == value-order
            }
        }
    }

    // stage 1.5: one butterfly step in registers (exact: u64 min over same set)
#pragma unroll
    for (int p = 0; p < PTILE; ++p) {
        unsigned long long o = __shfl_xor(best[p], 1, 64);
        best[p] = o < best[p] ? o : best[p];
    }
    if ((t & 1) == 0) {
#pragma unroll
        for (int p = 0; p < PTILE; ++p) s_cand[p][t >> 1] = best[p];
    }
    __syncthreads();

    {   // stage 2: 256 threads, each folds 8 of the 128 candidates of pixel t&15
        const int p = t & 15, g = t >> 4;
        unsigned long long m = s_cand[p][(g << 3)];
#pragma unroll
        for (int u = 1; u < 8; ++u) {
            unsigned long long v = s_cand[p][(g << 3) + u];
            m = v < m ? v : m;
        }
        s_part[p][g] = m;
    }
    __syncthreads();

    if (t < PTILE) {   // stage 3: final per-pixel min; packed low bits = first-index k
        unsigned long long m = s_part[t][0];
#pragma unroll
        for (int g = 1; g < 16; ++g) {
            unsigned long long v = s_part[t][g];
            m = v < m ? v : m;
        }
        const unsigned int k = (unsigned int)m;
        s_k[t] = k;
        out[IDX_OFF + pg0 + t] = (float)k;
    }
    __syncthreads();

    // epilogue: thread t -> pixel p=t&15, channels c = (t>>4) + 16u
    float lsum = 0.f;
    {
        const int p = t & 15, g = t >> 4;
        const int k = (int)s_k[p];
#pragma unroll
        for (int u = 0; u < 4; ++u) {
            const int c = g + (u << 4);
            float e    = emb[(size_t)k * CCH + c];
            float zc   = zb[(size_t)c * HW + p];
            float diff = __fsub_rn(e, zc);               // STE rounding as in R8
            out[((size_t)(b * CCH + c)) * HW + hw0 + p] = __fadd_rn(zc, diff);
            lsum = __builtin_fmaf(diff, diff, lsum);
        }
    }
#pragma unroll
    for (int off = 32; off > 0; off >>= 1) lsum += __shfl_down(lsum, off, 64);
    if (lane == 0) s_red[wave] = lsum;
    __syncthreads();
    if (t == 0) {
        float v = (s_red[0] + s_red[1] + s_red[2] + s_red[3]) * (1.0f / (float)Q_ELEMS);
        atomicAdd(out + LOSS0_OFF, v);   // codebook_loss
        atomicAdd(out + LOSS1_OFF, v);   // commitment_loss (same forward value)
    }
}

extern "C" void kernel_launch(void* const* d_in, const int* in_sizes, int n_in,
                              void* d_out, int out_size, void* d_ws, size_t ws_size,
                              hipStream_t stream) {
    const float* z   = (const float*)d_in[0];
    const float* emb = (const float*)d_in[1];
    float* out = (float*)d_out;
    float* se  = (float*)d_ws;                 // 1024 floats
    float* et  = se + KCODE;                   // 65536 floats (E^T)

    prep_kernel<<<dim3(16), dim3(256), 0, stream>>>(emb, se, et, out);
    vq_kernel<<<dim3(NPIX / PTILE), dim3(256), 0, stream>>>(z, emb, se, et, out);
}

// Round 12
// 191.435 us; speedup vs baseline: 8.4567x; 1.0595x over previous
//
#include <hip/hip_runtime.h>

#define NPIX   65536          // B*H*W
#define CCH    64
#define KCODE  1024
#define HW     4096
#define Q_ELEMS 4194304
#define LOSS0_OFF 4194304
#define LOSS1_OFF 4194305
#define IDX_OFF   4194306
#define PTILE  16             // pixels per block

// numpy pairwise_sum middle branch for n=64 on squares (bit-exact np.sum(x*x))
template <typename F>
__device__ __forceinline__ float np_pairwise64_sq(F v) {
    float r[8];
#pragma unroll
    for (int j = 0; j < 8; ++j) r[j] = __fmul_rn(v(j), v(j));
#pragma unroll
    for (int i = 8; i < 64; i += 8) {
#pragma unroll
        for (int j = 0; j < 8; ++j)
            r[j] = __fadd_rn(r[j], __fmul_rn(v(i + j), v(i + j)));
    }
    return __fadd_rn(
        __fadd_rn(__fadd_rn(r[0], r[1]), __fadd_rn(r[2], r[3])),
        __fadd_rn(__fadd_rn(r[4], r[5]), __fadd_rn(r[6], r[7])));
}

// prep v2 (verified absmax 0): LDS-tile transpose, coalesced on both sides.
__global__ void prep_kernel(const float* __restrict__ emb,
                            float* __restrict__ se, float* __restrict__ et,
                            float* __restrict__ out) {
    __shared__ float s_e[64][65];                      // +pad: conflict-free both axes
    const int t  = threadIdx.x;
    const int k0 = blockIdx.x << 6;
#pragma unroll
    for (int i = 0; i < 4; ++i) {
        const int q = (i << 8) + t;                    // float4 index 0..1023
        const float4 v = reinterpret_cast<const float4*>(emb + ((size_t)k0 << 6))[q];
        const int r = q >> 4, c4 = (q & 15) << 2;
        s_e[r][c4] = v.x; s_e[r][c4 + 1] = v.y; s_e[r][c4 + 2] = v.z; s_e[r][c4 + 3] = v.w;
    }
    __syncthreads();
    if (t < 64)
        se[k0 + t] = np_pairwise64_sq([&](int i) { return s_e[t][i]; });
#pragma unroll
    for (int i = 0; i < 16; ++i) {
        const int n = (i << 8) + t;                    // 0..4095
        const int c = n >> 6, kk = n & 63;
        et[((size_t)c << 10) + k0 + kk] = s_e[kk][c];  // wave: 256B contiguous
    }
    if ((blockIdx.x | t) == 0) { out[LOSS0_OFF] = 0.f; out[LOSS1_OFF] = 0.f; }
}

// main: EXACT R8 structure (130.6us, VGPR 52, W=4 -- the only spill-free
// point; R5-R11 established the operand economy is locally optimal).
// R12 probe: co-resident blocks run identical 64-FMA+drain rhythms and are
// phase-aligned by launch timing + the szz barrier -> all waves on a SIMD
// drain lgkmcnt simultaneously -> VALU idles at 64% despite 3 waves/SIMD.
// Fix attempt: pseudo-random entry s_sleep {0,128,256,384}cy per block
// (hashed blockIdx: robust to any block->CU mapping incl. 256-stride RR).
// No math touched -> absmax 0. Neutral result falsifies correlated-stall.
__launch_bounds__(256, 4)
__global__ void vq_kernel(const float* __restrict__ z,
                          const float* __restrict__ emb,
                          const float* __restrict__ se,
                          const float* __restrict__ et,
                          float* __restrict__ out) {
    __shared__ float s_szz[PTILE];
    __shared__ unsigned long long s_cand[PTILE][129];  // halved via shfl pre-reduce; +pad
    __shared__ unsigned long long s_part[PTILE][16];
    __shared__ unsigned int s_k[PTILE];
    __shared__ float s_red[4];

    {   // R12: de-phase co-resident blocks' stall windows (~1/4 period steps)
        const unsigned h = (blockIdx.x * 2654435761u) >> 30;   // 0..3 pseudo-random
        if (h == 1)      __builtin_amdgcn_s_sleep(2);          // ~128 cy
        else if (h == 2) __builtin_amdgcn_s_sleep(4);          // ~256 cy
        else if (h == 3) __builtin_amdgcn_s_sleep(6);          // ~384 cy
    }

    const int t    = threadIdx.x;
    const int lane = t & 63;
    const int wave = t >> 6;
    const int pg0  = blockIdx.x * PTILE;
    const int b    = pg0 >> 12;
    const int hw0  = pg0 & 4095;
    const float* zb = z + (size_t)b * CCH * HW + hw0;  // zb[c*HW + p], wave-uniform

    // szz for the block's 16 pixels (np order), lanes 0..15 of wave 0
    if (t < PTILE)
        s_szz[t] = np_pairwise64_sq([&](int i) { return zb[(size_t)i * HW + t]; });
    __syncthreads();

    // ---- main accumulation: acc[j][p] = sum_c z[c][p] * E^T[c][4t+j] ----
    float acc[4][PTILE];
#pragma unroll
    for (int j = 0; j < 4; ++j)
#pragma unroll
        for (int p = 0; p < PTILE; ++p) acc[j][p] = 0.f;

    const float* ecol = et + (t << 2);                 // 4 consecutive codes
#pragma unroll 4
    for (int c = 0; c < CCH; ++c) {
        const float4 evv = *reinterpret_cast<const float4*>(ecol + (c << 10));
        const float ev[4] = {evv.x, evv.y, evv.z, evv.w};
        float zrow[PTILE];                              // uniform -> s_load_dwordx16
#pragma unroll
        for (int p = 0; p < PTILE; ++p) zrow[p] = zb[(size_t)c * HW + p];
#pragma unroll
        for (int j = 0; j < 4; ++j)
#pragma unroll
            for (int p = 0; p < PTILE; ++p)
                acc[j][p] = __builtin_fmaf(zrow[p], ev[j], acc[j][p]);  // same chain as R2
    }

    // ---- finalize distances + per-thread best (tail; acc dies into best) ----
    float szzv[PTILE];
#pragma unroll
    for (int p = 0; p < PTILE; ++p) szzv[p] = s_szz[p];
    const float4 se4v = *reinterpret_cast<const float4*>(se + (t << 2));
    const float se4[4] = {se4v.x, se4v.y, se4v.z, se4v.w};

    unsigned long long best[PTILE];
#pragma unroll
    for (int p = 0; p < PTILE; ++p) best[p] = ~0ULL;

#pragma unroll
    for (int j = 0; j < 4; ++j) {
        const int kk = (t << 2) + j;
#pragma unroll
        for (int p = 0; p < PTILE; ++p) {
            // d = fl( fl(szz+se) - 2*dot )  (identical algebra to R2, absmax 0)
            float d = __fsub_rn(__fadd_rn(szzv[p], se4[j]), __fadd_rn(acc[j][p], acc[j][p]));
            unsigned long long cand =
                ((unsigned long long)__float_as_uint(d) << 32) | (unsigned)kk;
            best[p] = cand < best[p] ? cand : best[p];   // d>0 -> bit-order == value-order
        }
    }

    // stage 1.5: one butterfly step in registers (exact: u64 min over same set)
#pragma unroll
    for (int p = 0; p < PTILE; ++p) {
        unsigned long long o = __shfl_xor(best[p], 1, 64);
        best[p] = o < best[p] ? o : best[p];
    }
    if ((t & 1) == 0) {
#pragma unroll
        for (int p = 0; p < PTILE; ++p) s_cand[p][t >> 1] = best[p];
    }
    __syncthreads();

    {   // stage 2: 256 threads, each folds 8 of the 128 candidates of pixel t&15
        const int p = t & 15, g = t >> 4;
        unsigned long long m = s_cand[p][(g << 3)];
#pragma unroll
        for (int u = 1; u < 8; ++u) {
            unsigned long long v = s_cand[p][(g << 3) + u];
            m = v < m ? v : m;
        }
        s_part[p][g] = m;
    }
    __syncthreads();

    if (t < PTILE) {   // stage 3: final per-pixel min; packed low bits = first-index k
        unsigned long long m = s_part[t][0];
#pragma unroll
        for (int g = 1; g < 16; ++g) {
            unsigned long long v = s_part[t][g];
            m = v < m ? v : m;
        }
        const unsigned int k = (unsigned int)m;
        s_k[t] = k;
        out[IDX_OFF + pg0 + t] = (float)k;
    }
    __syncthreads();

    // epilogue: thread t -> pixel p=t&15, channels c = (t>>4) + 16u
    float lsum = 0.f;
    {
        const int p = t & 15, g = t >> 4;
        const int k = (int)s_k[p];
#pragma unroll
        for (int u = 0; u < 4; ++u) {
            const int c = g + (u << 4);
            float e    = emb[(size_t)k * CCH + c];
            float zc   = zb[(size_t)c * HW + p];
            float diff = __fsub_rn(e, zc);               // STE rounding as in R2
            out[((size_t)(b * CCH + c)) * HW + hw0 + p] = __fadd_rn(zc, diff);
            lsum = __builtin_fmaf(diff, diff, lsum);
        }
    }
#pragma unroll
    for (int off = 32; off > 0; off >>= 1) lsum += __shfl_down(lsum, off, 64);
    if (lane == 0) s_red[wave] = lsum;
    __syncthreads();
    if (t == 0) {
        float v = (s_red[0] + s_red[1] + s_red[2] + s_red[3]) * (1.0f / (float)Q_ELEMS);
        atomicAdd(out + LOSS0_OFF, v);   // codebook_loss
        atomicAdd(out + LOSS1_OFF, v);   // commitment_loss (same forward value)
    }
}

extern "C" void kernel_launch(void* const* d_in, const int* in_sizes, int n_in,
                              void* d_out, int out_size, void* d_ws, size_t ws_size,
                              hipStream_t stream) {
    const float* z   = (const float*)d_in[0];
    const float* emb = (const float*)d_in[1];
    float* out = (float*)d_out;
    float* se  = (float*)d_ws;                 // 1024 floats
    float* et  = se + KCODE;                   // 65536 floats (E^T)

    prep_kernel<<<dim3(16), dim3(256), 0, stream>>>(emb, se, et, out);
    vq_kernel<<<dim3(NPIX / PTILE), dim3(256), 0, stream>>>(z, emb, se, et, out);
}

// Round 15
// 189.767 us; speedup vs baseline: 8.5311x; 1.0088x over previous
//
#include <hip/hip_runtime.h>

#define NPIX   65536          // B*H*W
#define CCH    64
#define KCODE  1024
#define HW     4096
#define Q_ELEMS 4194304
#define LOSS0_OFF 4194304
#define LOSS1_OFF 4194305
#define IDX_OFF   4194306
#define PTILE  16             // pixels per block

// numpy pairwise_sum middle branch for n=64 on squares (bit-exact np.sum(x*x))
template <typename F>
__device__ __forceinline__ float np_pairwise64_sq(F v) {
    float r[8];
#pragma unroll
    for (int j = 0; j < 8; ++j) r[j] = __fmul_rn(v(j), v(j));
#pragma unroll
    for (int i = 8; i < 64; i += 8) {
#pragma unroll
        for (int j = 0; j < 8; ++j)
            r[j] = __fadd_rn(r[j], __fmul_rn(v(i + j), v(i + j)));
    }
    return __fadd_rn(
        __fadd_rn(__fadd_rn(r[0], r[1]), __fadd_rn(r[2], r[3])),
        __fadd_rn(__fadd_rn(r[4], r[5]), __fadd_rn(r[6], r[7])));
}

// prep v2 (verified absmax 0): LDS-tile transpose, coalesced on both sides.
__global__ void prep_kernel(const float* __restrict__ emb,
                            float* __restrict__ se, float* __restrict__ et,
                            float* __restrict__ out) {
    __shared__ float s_e[64][65];                      // +pad: conflict-free both axes
    const int t  = threadIdx.x;
    const int k0 = blockIdx.x << 6;
#pragma unroll
    for (int i = 0; i < 4; ++i) {
        const int q = (i << 8) + t;                    // float4 index 0..1023
        const float4 v = reinterpret_cast<const float4*>(emb + ((size_t)k0 << 6))[q];
        const int r = q >> 4, c4 = (q & 15) << 2;
        s_e[r][c4] = v.x; s_e[r][c4 + 1] = v.y; s_e[r][c4 + 2] = v.z; s_e[r][c4 + 3] = v.w;
    }
    __syncthreads();
    if (t < 64)
        se[k0 + t] = np_pairwise64_sq([&](int i) { return s_e[t][i]; });
#pragma unroll
    for (int i = 0; i < 16; ++i) {
        const int n = (i << 8) + t;                    // 0..4095
        const int c = n >> 6, kk = n & 63;
        et[((size_t)c << 10) + k0 + kk] = s_e[kk][c];  // wave: 256B contiguous
    }
    if ((blockIdx.x | t) == 0) { out[LOSS0_OFF] = 0.f; out[LOSS1_OFF] = 0.f; }
}

// main: EXACT R8 structure (130.6us, VGPR 52, no spills).
// R15: same hypothesis as R13/R14 (both infra-failed), different encoding:
// amdgpu_waves_per_eu(4, 8) -- min 4 keeps the W=4 register budget (64-VGPR
// cap, 52 used, spill-impossible), max 8 explicitly ALLOWS residency up to
// the LDS limit (18944B -> 8 blocks/CU). Decouples the two effects the
// __launch_bounds__ 2nd arg fused (budget ~256/W AND residency ~0.78W).
// Tripwire: VGPR <= 48 or FETCH > 25 MB => squeezed, revert to plain (256,4).
// Neutral => residency is scheduler-imposed; conclude structural analysis.
__launch_bounds__(256)
__attribute__((amdgpu_waves_per_eu(4, 8)))
__global__ void vq_kernel(const float* __restrict__ z,
                          const float* __restrict__ emb,
                          const float* __restrict__ se,
                          const float* __restrict__ et,
                          float* __restrict__ out) {
    __shared__ float s_szz[PTILE];
    __shared__ unsigned long long s_cand[PTILE][129];  // halved via shfl pre-reduce; +pad
    __shared__ unsigned long long s_part[PTILE][16];
    __shared__ unsigned int s_k[PTILE];
    __shared__ float s_red[4];

    const int t    = threadIdx.x;
    const int lane = t & 63;
    const int wave = t >> 6;
    const int pg0  = blockIdx.x * PTILE;
    const int b    = pg0 >> 12;
    const int hw0  = pg0 & 4095;
    const float* zb = z + (size_t)b * CCH * HW + hw0;  // zb[c*HW + p], wave-uniform

    // szz for the block's 16 pixels (np order), lanes 0..15 of wave 0
    if (t < PTILE)
        s_szz[t] = np_pairwise64_sq([&](int i) { return zb[(size_t)i * HW + t]; });
    __syncthreads();

    // ---- main accumulation: acc[j][p] = sum_c z[c][p] * E^T[c][4t+j] ----
    float acc[4][PTILE];
#pragma unroll
    for (int j = 0; j < 4; ++j)
#pragma unroll
        for (int p = 0; p < PTILE; ++p) acc[j][p] = 0.f;

    const float* ecol = et + (t << 2);                 // 4 consecutive codes
#pragma unroll 4
    for (int c = 0; c < CCH; ++c) {
        const float4 evv = *reinterpret_cast<const float4*>(ecol + (c << 10));
        const float ev[4] = {evv.x, evv.y, evv.z, evv.w};
        float zrow[PTILE];                              // uniform -> s_load_dwordx16
#pragma unroll
        for (int p = 0; p < PTILE; ++p) zrow[p] = zb[(size_t)c * HW + p];
#pragma unroll
        for (int j = 0; j < 4; ++j)
#pragma unroll
            for (int p = 0; p < PTILE; ++p)
                acc[j][p] = __builtin_fmaf(zrow[p], ev[j], acc[j][p]);  // same chain as R2
    }

    // ---- finalize distances + per-thread best (tail; acc dies into best) ----
    float szzv[PTILE];
#pragma unroll
    for (int p = 0; p < PTILE; ++p) szzv[p] = s_szz[p];
    const float4 se4v = *reinterpret_cast<const float4*>(se + (t << 2));
    const float se4[4] = {se4v.x, se4v.y, se4v.z, se4v.w};

    unsigned long long best[PTILE];
#pragma unroll
    for (int p = 0; p < PTILE; ++p) best[p] = ~0ULL;

#pragma unroll
    for (int j = 0; j < 4; ++j) {
        const int kk = (t << 2) + j;
#pragma unroll
        for (int p = 0; p < PTILE; ++p) {
            // d = fl( fl(szz+se) - 2*dot )  (identical algebra to R2, absmax 0)
            float d = __fsub_rn(__fadd_rn(szzv[p], se4[j]), __fadd_rn(acc[j][p], acc[j][p]));
            unsigned long long cand =
                ((unsigned long long)__float_as_uint(d) << 32) | (unsigned)kk;
            best[p] = cand < best[p] ? cand : best[p];   // d>0 -> bit-order == value-order
        }
    }

    // stage 1.5: one butterfly step in registers (exact: u64 min over same set)
#pragma unroll
    for (int p = 0; p < PTILE; ++p) {
        unsigned long long o = __shfl_xor(best[p], 1, 64);
        best[p] = o < best[p] ? o : best[p];
    }
    if ((t & 1) == 0) {
#pragma unroll
        for (int p = 0; p < PTILE; ++p) s_cand[p][t >> 1] = best[p];
    }
    __syncthreads();

    {   // stage 2: 256 threads, each folds 8 of the 128 candidates of pixel t&15
        const int p = t & 15, g = t >> 4;
        unsigned long long m = s_cand[p][(g << 3)];
#pragma unroll
        for (int u = 1; u < 8; ++u) {
            unsigned long long v = s_cand[p][(g << 3) + u];
            m = v < m ? v : m;
        }
        s_part[p][g] = m;
    }
    __syncthreads();

    if (t < PTILE) {   // stage 3: final per-pixel min; packed low bits = first-index k
        unsigned long long m = s_part[t][0];
#pragma unroll
        for (int g = 1; g < 16; ++g) {
            unsigned long long v = s_part[t][g];
            m = v < m ? v : m;
        }
        const unsigned int k = (unsigned int)m;
        s_k[t] = k;
        out[IDX_OFF + pg0 + t] = (float)k;
    }
    __syncthreads();

    // epilogue: thread t -> pixel p=t&15, channels c = (t>>4) + 16u
    float lsum = 0.f;
    {
        const int p = t & 15, g = t >> 4;
        const int k = (int)s_k[p];
#pragma unroll
        for (int u = 0; u < 4; ++u) {
            const int c = g + (u << 4);
            float e    = emb[(size_t)k * CCH + c];
            float zc   = zb[(size_t)c * HW + p];
            float diff = __fsub_rn(e, zc);               // STE rounding as in R2
            out[((size_t)(b * CCH + c)) * HW + hw0 + p] = __fadd_rn(zc, diff);
            lsum = __builtin_fmaf(diff, diff, lsum);
        }
    }
#pragma unroll
    for (int off = 32; off > 0; off >>= 1) lsum += __shfl_down(lsum, off, 64);
    if (lane == 0) s_red[wave] = lsum;
    __syncthreads();
    if (t == 0) {
        float v = (s_red[0] + s_red[1] + s_red[2] + s_red[3]) * (1.0f / (float)Q_ELEMS);
        atomicAdd(out + LOSS0_OFF, v);   // codebook_loss
        atomicAdd(out + LOSS1_OFF, v);   // commitment_loss (same forward value)
    }
}

extern "C" void kernel_launch(void* const* d_in, const int* in_sizes, int n_in,
                              void* d_out, int out_size, void* d_ws, size_t ws_size,
                              hipStream_t stream) {
    const float* z   = (const float*)d_in[0];
    const float* emb = (const float*)d_in[1];
    float* out = (float*)d_out;
    float* se  = (float*)d_ws;                 // 1024 floats
    float* et  = se + KCODE;                   // 65536 floats (E^T)

    prep_kernel<<<dim3(16), dim3(256), 0, stream>>>(emb, se, et, out);
    vq_kernel<<<dim3(NPIX / PTILE), dim3(256), 0, stream>>>(z, emb, se, et, out);
}

// Round 16
// 189.238 us; speedup vs baseline: 8.5549x; 1.0028x over previous
//
#include <hip/hip_runtime.h>

#define NPIX   65536          // B*H*W
#define CCH    64
#define KCODE  1024
#define HW     4096
#define Q_ELEMS 4194304
#define LOSS0_OFF 4194304
#define LOSS1_OFF 4194305
#define IDX_OFF   4194306
#define PTILE  16             // pixels per block

// numpy pairwise_sum middle branch for n=64 on squares (bit-exact np.sum(x*x))
template <typename F>
__device__ __forceinline__ float np_pairwise64_sq(F v) {
    float r[8];
#pragma unroll
    for (int j = 0; j < 8; ++j) r[j] = __fmul_rn(v(j), v(j));
#pragma unroll
    for (int i = 8; i < 64; i += 8) {
#pragma unroll
        for (int j = 0; j < 8; ++j)
            r[j] = __fadd_rn(r[j], __fmul_rn(v(i + j), v(i + j)));
    }
    return __fadd_rn(
        __fadd_rn(__fadd_rn(r[0], r[1]), __fadd_rn(r[2], r[3])),
        __fadd_rn(__fadd_rn(r[4], r[5]), __fadd_rn(r[6], r[7])));
}

// prep v2 (verified absmax 0): LDS-tile transpose, coalesced on both sides.
__global__ void prep_kernel(const float* __restrict__ emb,
                            float* __restrict__ se, float* __restrict__ et,
                            float* __restrict__ out) {
    __shared__ float s_e[64][65];                      // +pad: conflict-free both axes
    const int t  = threadIdx.x;
    const int k0 = blockIdx.x << 6;
#pragma unroll
    for (int i = 0; i < 4; ++i) {
        const int q = (i << 8) + t;                    // float4 index 0..1023
        const float4 v = reinterpret_cast<const float4*>(emb + ((size_t)k0 << 6))[q];
        const int r = q >> 4, c4 = (q & 15) << 2;
        s_e[r][c4] = v.x; s_e[r][c4 + 1] = v.y; s_e[r][c4 + 2] = v.z; s_e[r][c4 + 3] = v.w;
    }
    __syncthreads();
    if (t < 64)
        se[k0 + t] = np_pairwise64_sq([&](int i) { return s_e[t][i]; });
#pragma unroll
    for (int i = 0; i < 16; ++i) {
        const int n = (i << 8) + t;                    // 0..4095
        const int c = n >> 6, kk = n & 63;
        et[((size_t)c << 10) + k0 + kk] = s_e[kk][c];  // wave: 256B contiguous
    }
    if ((blockIdx.x | t) == 0) { out[LOSS0_OFF] = 0.f; out[LOSS1_OFF] = 0.f; }
}

// main: EXACT R8 structure. R16 probe: amdgpu_waves_per_eu(2, 8).
// W-series allocator targets: W=2->100, W=4->52, W=6->40, W=8->32 VGPR.
// R8 holds 64 LIVE accumulators in 52 arch VGPRs => ~12-24 values are AGPR-
// parked, costing v_accvgpr_read/write in the hot loop = the ~29us of
// non-FMA VALU issue (83us measured vs 54.6us FMA floor). min=2 raises the
// allocator target to ~100 => all accs in arch VGPRs, zero parking; max=8
// keeps residency unconstrained (R15: max is harmless; plateau ~3 waves/SIMD
// is scheduler-imposed, and VGPR 100 still allows 5).
// Tripwire: FETCH > 25 MB => unexpected scratch; revert.
__launch_bounds__(256)
__attribute__((amdgpu_waves_per_eu(2, 8)))
__global__ void vq_kernel(const float* __restrict__ z,
                          const float* __restrict__ emb,
                          const float* __restrict__ se,
                          const float* __restrict__ et,
                          float* __restrict__ out) {
    __shared__ float s_szz[PTILE];
    __shared__ unsigned long long s_cand[PTILE][129];  // halved via shfl pre-reduce; +pad
    __shared__ unsigned long long s_part[PTILE][16];
    __shared__ unsigned int s_k[PTILE];
    __shared__ float s_red[4];

    const int t    = threadIdx.x;
    const int lane = t & 63;
    const int wave = t >> 6;
    const int pg0  = blockIdx.x * PTILE;
    const int b    = pg0 >> 12;
    const int hw0  = pg0 & 4095;
    const float* zb = z + (size_t)b * CCH * HW + hw0;  // zb[c*HW + p], wave-uniform

    // szz for the block's 16 pixels (np order), lanes 0..15 of wave 0
    if (t < PTILE)
        s_szz[t] = np_pairwise64_sq([&](int i) { return zb[(size_t)i * HW + t]; });
    __syncthreads();

    // ---- main accumulation: acc[j][p] = sum_c z[c][p] * E^T[c][4t+j] ----
    float acc[4][PTILE];
#pragma unroll
    for (int j = 0; j < 4; ++j)
#pragma unroll
        for (int p = 0; p < PTILE; ++p) acc[j][p] = 0.f;

    const float* ecol = et + (t << 2);                 // 4 consecutive codes
#pragma unroll 4
    for (int c = 0; c < CCH; ++c) {
        const float4 evv = *reinterpret_cast<const float4*>(ecol + (c << 10));
        const float ev[4] = {evv.x, evv.y, evv.z, evv.w};
        float zrow[PTILE];                              // uniform -> s_load_dwordx16
#pragma unroll
        for (int p = 0; p < PTILE; ++p) zrow[p] = zb[(size_t)c * HW + p];
#pragma unroll
        for (int j = 0; j < 4; ++j)
#pragma unroll
            for (int p = 0; p < PTILE; ++p)
                acc[j][p] = __builtin_fmaf(zrow[p], ev[j], acc[j][p]);  // same chain as R2
    }

    // ---- finalize distances + per-thread best (tail; acc dies into best) ----
    float szzv[PTILE];
#pragma unroll
    for (int p = 0; p < PTILE; ++p) szzv[p] = s_szz[p];
    const float4 se4v = *reinterpret_cast<const float4*>(se + (t << 2));
    const float se4[4] = {se4v.x, se4v.y, se4v.z, se4v.w};

    unsigned long long best[PTILE];
#pragma unroll
    for (int p = 0; p < PTILE; ++p) best[p] = ~0ULL;

#pragma unroll
    for (int j = 0; j < 4; ++j) {
        const int kk = (t << 2) + j;
#pragma unroll
        for (int p = 0; p < PTILE; ++p) {
            // d = fl( fl(szz+se) - 2*dot )  (identical algebra to R2, absmax 0)
            float d = __fsub_rn(__fadd_rn(szzv[p], se4[j]), __fadd_rn(acc[j][p], acc[j][p]));
            unsigned long long cand =
                ((unsigned long long)__float_as_uint(d) << 32) | (unsigned)kk;
            best[p] = cand < best[p] ? cand : best[p];   // d>0 -> bit-order == value-order
        }
    }

    // stage 1.5: one butterfly step in registers (exact: u64 min over same set)
#pragma unroll
    for (int p = 0; p < PTILE; ++p) {
        unsigned long long o = __shfl_xor(best[p], 1, 64);
        best[p] = o < best[p] ? o : best[p];
    }
    if ((t & 1) == 0) {
#pragma unroll
        for (int p = 0; p < PTILE; ++p) s_cand[p][t >> 1] = best[p];
    }
    __syncthreads();

    {   // stage 2: 256 threads, each folds 8 of the 128 candidates of pixel t&15
        const int p = t & 15, g = t >> 4;
        unsigned long long m = s_cand[p][(g << 3)];
#pragma unroll
        for (int u = 1; u < 8; ++u) {
            unsigned long long v = s_cand[p][(g << 3) + u];
            m = v < m ? v : m;
        }
        s_part[p][g] = m;
    }
    __syncthreads();

    if (t < PTILE) {   // stage 3: final per-pixel min; packed low bits = first-index k
        unsigned long long m = s_part[t][0];
#pragma unroll
        for (int g = 1; g < 16; ++g) {
            unsigned long long v = s_part[t][g];
            m = v < m ? v : m;
        }
        const unsigned int k = (unsigned int)m;
        s_k[t] = k;
        out[IDX_OFF + pg0 + t] = (float)k;
    }
    __syncthreads();

    // epilogue: thread t -> pixel p=t&15, channels c = (t>>4) + 16u
    float lsum = 0.f;
    {
        const int p = t & 15, g = t >> 4;
        const int k = (int)s_k[p];
#pragma unroll
        for (int u = 0; u < 4; ++u) {
            const int c = g + (u << 4);
            float e    = emb[(size_t)k * CCH + c];
            float zc   = zb[(size_t)c * HW + p];
            float diff = __fsub_rn(e, zc);               // STE rounding as in R2
            out[((size_t)(b * CCH + c)) * HW + hw0 + p] = __fadd_rn(zc, diff);
            lsum = __builtin_fmaf(diff, diff, lsum);
        }
    }
#pragma unroll
    for (int off = 32; off > 0; off >>= 1) lsum += __shfl_down(lsum, off, 64);
    if (lane == 0) s_red[wave] = lsum;
    __syncthreads();
    if (t == 0) {
        float v = (s_red[0] + s_red[1] + s_red[2] + s_red[3]) * (1.0f / (float)Q_ELEMS);
        atomicAdd(out + LOSS0_OFF, v);   // codebook_loss
        atomicAdd(out + LOSS1_OFF, v);   // commitment_loss (same forward value)
    }
}

extern "C" void kernel_launch(void* const* d_in, const int* in_sizes, int n_in,
                              void* d_out, int out_size, void* d_ws, size_t ws_size,
                              hipStream_t stream) {
    const float* z   = (const float*)d_in[0];
    const float* emb = (const float*)d_in[1];
    float* out = (float*)d_out;
    float* se  = (float*)d_ws;                 // 1024 floats
    float* et  = se + KCODE;                   // 65536 floats (E^T)

    prep_kernel<<<dim3(16), dim3(256), 0, stream>>>(emb, se, et, out);
    vq_kernel<<<dim3(NPIX / PTILE), dim3(256), 0, stream>>>(z, emb, se, et, out);
}